// Round 1
// baseline (1065.573 us; speedup 1.0000x reference)
//
#include <hip/hip_runtime.h>

#define Bn 16
#define Cn 128
#define Hn 128
#define Wn 128
#define Nn (Hn * Wn)   // 16384

// ---------------------------------------------------------------------------
// Kernel 1: Gram matrix G[b] = f · f^T  (fp64 accumulate, split-K + atomics)
// grid = Bn * 4 tiles(2x2 of 64) * 8 ksplit = 512 blocks, 256 thr
// each thread: 4x4 micro-tile, fp64 accumulators
// ---------------------------------------------------------------------------
__global__ __launch_bounds__(256) void gram_kernel(const float* __restrict__ x,
                                                   double* __restrict__ G) {
    const int bid  = blockIdx.x;
    const int ks   = bid & 7;          // k-split 0..7 (2048 each)
    const int tile = (bid >> 3) & 3;   // 2x2 tile of 64x64
    const int b    = bid >> 5;         // batch
    const int ti   = (tile >> 1) << 6; // row (c) base
    const int tj   = (tile & 1) << 6;  // col (d) base
    const float* __restrict__ fb = x + (size_t)b * Cn * Nn;
    const int k0 = ks << 11;

    __shared__ float As[64][33];   // [row][k], pad->2-way max conflicts
    __shared__ float Bs[64][33];

    const int tid = threadIdx.x;
    const int tx = tid & 15, ty = tid >> 4;
    const int lr = tid >> 3;           // 0..31 staging row
    const int lk = (tid & 7) << 2;     // 0,4,..,28 staging k

    double acc[4][4];
#pragma unroll
    for (int i = 0; i < 4; ++i)
#pragma unroll
        for (int j = 0; j < 4; ++j) acc[i][j] = 0.0;

    for (int kk = k0; kk < k0 + 2048; kk += 32) {
        __syncthreads();
#pragma unroll
        for (int rr = 0; rr < 2; ++rr) {
            const int r = lr + (rr << 5);
            const float4 av = *(const float4*)(fb + (size_t)(ti + r) * Nn + kk + lk);
            As[r][lk + 0] = av.x; As[r][lk + 1] = av.y;
            As[r][lk + 2] = av.z; As[r][lk + 3] = av.w;
            const float4 bv = *(const float4*)(fb + (size_t)(tj + r) * Nn + kk + lk);
            Bs[r][lk + 0] = bv.x; Bs[r][lk + 1] = bv.y;
            Bs[r][lk + 2] = bv.z; Bs[r][lk + 3] = bv.w;
        }
        __syncthreads();
#pragma unroll
        for (int k = 0; k < 32; ++k) {
            float a[4], bb[4];
#pragma unroll
            for (int i = 0; i < 4; ++i) a[i] = As[(ty << 2) + i][k];
#pragma unroll
            for (int j = 0; j < 4; ++j) bb[j] = Bs[(tx << 2) + j][k];
#pragma unroll
            for (int i = 0; i < 4; ++i)
#pragma unroll
                for (int j = 0; j < 4; ++j)
                    acc[i][j] += (double)a[i] * (double)bb[j];
        }
    }

    double* __restrict__ Gb = G + (size_t)b * Cn * Cn;
#pragma unroll
    for (int i = 0; i < 4; ++i)
#pragma unroll
        for (int j = 0; j < 4; ++j)
            atomicAdd(&Gb[(size_t)(ti + (ty << 2) + i) * Cn + tj + (tx << 2) + j],
                      acc[i][j]);
}

// ---------------------------------------------------------------------------
// Kernel 2: M[row][d] = rowmax(G[row]) - G[row][d], double -> float
// grid = Bn*Cn blocks of 128 threads
// ---------------------------------------------------------------------------
__global__ __launch_bounds__(128) void maxsub_kernel(const double* __restrict__ G,
                                                     float* __restrict__ M) {
    const int row = blockIdx.x;
    const int l = threadIdx.x;
    const double v = G[(size_t)row * Cn + l];
    __shared__ double red[128];
    red[l] = v;
    __syncthreads();
#pragma unroll
    for (int s = 64; s > 0; s >>= 1) {
        if (l < s) red[l] = fmax(red[l], red[l + s]);
        __syncthreads();
    }
    M[(size_t)row * Cn + l] = (float)(red[0] - v);
}

// ---------------------------------------------------------------------------
// Kernel 3: Y[b] = M[b] @ f[b]   ([128x128] x [128x16384]), fp64 accumulate
// grid = Bn * 2 ctiles * 256 ntiles = 8192 blocks, 256 thr, 64x64 tile
// ---------------------------------------------------------------------------
__global__ __launch_bounds__(256) void ymm_kernel(const float* __restrict__ M,
                                                  const float* __restrict__ x,
                                                  float* __restrict__ Y) {
    const int bid = blockIdx.x;
    const int nt = bid & 255;
    const int ct = (bid >> 8) & 1;
    const int b  = bid >> 9;
    const int nbase = nt << 6;
    const int cbase = ct << 6;
    const float* __restrict__ fb = x + (size_t)b * Cn * Nn;
    const float* __restrict__ Mb = M + (size_t)b * Cn * Cn;

    __shared__ float As[64][33];   // [c][k]
    __shared__ float Bs[32][65];   // [k][n]

    const int tid = threadIdx.x;
    const int tx = tid & 15, ty = tid >> 4;

    double acc[4][4];
#pragma unroll
    for (int i = 0; i < 4; ++i)
#pragma unroll
        for (int j = 0; j < 4; ++j) acc[i][j] = 0.0;

    const int lrA = tid >> 3;          // 0..31
    const int lkA = (tid & 7) << 2;    // 0..28
    const int ldB = tid >> 4;          // 0..15
    const int lnB = (tid & 15) << 2;   // 0..60

    for (int kk = 0; kk < Cn; kk += 32) {
        __syncthreads();
#pragma unroll
        for (int rr = 0; rr < 2; ++rr) {
            const int r = lrA + (rr << 5);
            const float4 av = *(const float4*)(Mb + (size_t)(cbase + r) * Cn + kk + lkA);
            As[r][lkA + 0] = av.x; As[r][lkA + 1] = av.y;
            As[r][lkA + 2] = av.z; As[r][lkA + 3] = av.w;
        }
#pragma unroll
        for (int dd = 0; dd < 2; ++dd) {
            const int d = ldB + (dd << 4);
            const float4 bv = *(const float4*)(fb + (size_t)(kk + d) * Nn + nbase + lnB);
            Bs[d][lnB + 0] = bv.x; Bs[d][lnB + 1] = bv.y;
            Bs[d][lnB + 2] = bv.z; Bs[d][lnB + 3] = bv.w;
        }
        __syncthreads();
#pragma unroll
        for (int k = 0; k < 32; ++k) {
            float a[4], bb[4];
#pragma unroll
            for (int i = 0; i < 4; ++i) a[i] = As[(ty << 2) + i][k];
#pragma unroll
            for (int j = 0; j < 4; ++j) bb[j] = Bs[k][(tx << 2) + j];
#pragma unroll
            for (int i = 0; i < 4; ++i)
#pragma unroll
                for (int j = 0; j < 4; ++j)
                    acc[i][j] += (double)a[i] * (double)bb[j];
        }
    }

    float* __restrict__ Yb = Y + (size_t)b * Cn * Nn;
#pragma unroll
    for (int i = 0; i < 4; ++i) {
        float4 o;
        o.x = (float)acc[i][0]; o.y = (float)acc[i][1];
        o.z = (float)acc[i][2]; o.w = (float)acc[i][3];
        *(float4*)(Yb + (size_t)(cbase + (ty << 2) + i) * Nn + nbase + (tx << 2)) = o;
    }
}

// ---------------------------------------------------------------------------
// Kernel 4: depthwise 3x3 conv, SAME zero padding, + bias
// one thread per output element
// ---------------------------------------------------------------------------
__global__ __launch_bounds__(256) void dwconv_kernel(const float* __restrict__ Yin,
                                                     const float* __restrict__ wgt,
                                                     const float* __restrict__ bias,
                                                     float* __restrict__ Z) {
    const int idx = blockIdx.x * 256 + threadIdx.x;
    const int w = idx & 127;
    const int h = (idx >> 7) & 127;
    const int c = (idx >> 14) & 127;   // channel within batch
    const float* __restrict__ plane = Yin + (size_t)(idx >> 14) * Nn; // (b*C+c) plane
    const float* __restrict__ wc = wgt + c * 9;
    float s = bias[c];
#pragma unroll
    for (int kh = 0; kh < 3; ++kh) {
        const int hh = h + kh - 1;
        if (hh < 0 || hh >= Hn) continue;
#pragma unroll
        for (int kw = 0; kw < 3; ++kw) {
            const int ww = w + kw - 1;
            if (ww < 0 || ww >= Wn) continue;
            s += wc[kh * 3 + kw] * plane[hh * Wn + ww];
        }
    }
    Z[idx] = s;
}

// ---------------------------------------------------------------------------
// Kernel 5: softmax over W (rows of 128, in-place on Z==atten buffer)
//           + out = gamma * atten + x.  One wave (64 lanes) per row.
// ---------------------------------------------------------------------------
__global__ __launch_bounds__(256) void softmax_final_kernel(const float* __restrict__ Z,
                                                            const float* __restrict__ x,
                                                            const float* __restrict__ gamma,
                                                            float* __restrict__ out,
                                                            float* __restrict__ atten) {
    const int gtid = blockIdx.x * 256 + threadIdx.x;
    const int row = gtid >> 6;                 // B*C*H rows
    const int lane = threadIdx.x & 63;
    const size_t base = (size_t)row * Wn;

    const float v0 = Z[base + lane];
    const float v1 = Z[base + lane + 64];

    float m = fmaxf(v0, v1);
#pragma unroll
    for (int off = 32; off > 0; off >>= 1) m = fmaxf(m, __shfl_xor(m, off));

    const float e0 = __expf(v0 - m);
    const float e1 = __expf(v1 - m);
    float s = e0 + e1;
#pragma unroll
    for (int off = 32; off > 0; off >>= 1) s += __shfl_xor(s, off);

    const float inv = 1.0f / s;
    const float a0 = e0 * inv;
    const float a1 = e1 * inv;
    const float g = gamma[0];

    atten[base + lane]      = a0;
    atten[base + lane + 64] = a1;
    out[base + lane]      = fmaf(g, a0, x[base + lane]);
    out[base + lane + 64] = fmaf(g, a1, x[base + lane + 64]);
}

// ---------------------------------------------------------------------------
extern "C" void kernel_launch(void* const* d_in, const int* in_sizes, int n_in,
                              void* d_out, int out_size, void* d_ws, size_t ws_size,
                              hipStream_t stream) {
    const float* x     = (const float*)d_in[0];
    const float* wgt   = (const float*)d_in[1];
    const float* bias  = (const float*)d_in[2];
    const float* gamma = (const float*)d_in[3];

    float* out   = (float*)d_out;
    float* atten = out + (size_t)Bn * Cn * Nn;   // second output region

    double* G = (double*)d_ws;                               // 2 MB
    float*  M = (float*)(G + (size_t)Bn * Cn * Cn);          // +1 MB
    float*  Y = out;   // reuse out-region as Y scratch; overwritten last

    // G must start at zero (ws is poisoned 0xAA before every call)
    hipMemsetAsync(G, 0, sizeof(double) * (size_t)Bn * Cn * Cn, stream);

    gram_kernel<<<Bn * 4 * 8, 256, 0, stream>>>(x, G);
    maxsub_kernel<<<Bn * Cn, 128, 0, stream>>>(G, M);
    ymm_kernel<<<Bn * 2 * 256, 256, 0, stream>>>(M, x, Y);
    dwconv_kernel<<<(Bn * Cn * Nn) / 256, 256, 0, stream>>>(Y, wgt, bias, atten);
    // softmax in-place on atten region; writes final out over Y (no longer needed)
    softmax_final_kernel<<<(Bn * Cn * Hn) / 4, 256, 0, stream>>>(atten, x, gamma, out, atten);
}

// Round 2
// 639.226 us; speedup vs baseline: 1.6670x; 1.6670x over previous
//
#include <hip/hip_runtime.h>

#define Bn 16
#define Cn 128
#define Hn 128
#define Wn 128
#define Nn (Hn * Wn)   // 16384

// ---------------------------------------------------------------------------
// Kernel 1: Gram matrix G[b] = f . f^T, fp32 accumulate, split-K(32) + atomics.
// grid = 16 b * 32 ksplit = 512 blocks, 256 thr. Tile = full 128x128 (A==B
// fragments from ONE staged buffer). Micro-tile 8x8 split-cols.
// ---------------------------------------------------------------------------
__global__ __launch_bounds__(256) void gram_kernel(const float* __restrict__ x,
                                                   float* __restrict__ G) {
    const int bid = blockIdx.x;
    const int ks  = bid & 31;          // k-split 0..31 (512 each)
    const int b   = bid >> 5;
    const float* __restrict__ fb = x + (size_t)b * Cn * Nn;
    const int k0 = ks << 9;

    __shared__ __align__(16) float S[32][132];   // [k][c]

    const int tid = threadIdx.x;
    const int tx = tid & 15, ty = tid >> 4;      // 16x16 thread grid

    float acc[8][8];
#pragma unroll
    for (int i = 0; i < 8; ++i)
#pragma unroll
        for (int j = 0; j < 8; ++j) acc[i][j] = 0.0f;

    for (int kk = 0; kk < 512; kk += 32) {
        __syncthreads();
        // stage 128 rows x 32 k (transposed): 1024 float4, 4 per thread
#pragma unroll
        for (int p = 0; p < 4; ++p) {
            const int q  = tid + (p << 8);
            const int c  = q >> 3;           // 0..127
            const int k4 = (q & 7) << 2;     // 0,4,...,28
            const float4 v = *(const float4*)(fb + (size_t)c * Nn + k0 + kk + k4);
            S[k4 + 0][c] = v.x; S[k4 + 1][c] = v.y;
            S[k4 + 2][c] = v.z; S[k4 + 3][c] = v.w;
        }
        __syncthreads();
#pragma unroll
        for (int k = 0; k < 32; ++k) {
            const float4 a0 = *(const float4*)&S[k][4 * ty];
            const float4 a1 = *(const float4*)&S[k][64 + 4 * ty];
            const float4 b0 = *(const float4*)&S[k][4 * tx];
            const float4 b1 = *(const float4*)&S[k][64 + 4 * tx];
            const float av[8] = {a0.x, a0.y, a0.z, a0.w, a1.x, a1.y, a1.z, a1.w};
            const float bv[8] = {b0.x, b0.y, b0.z, b0.w, b1.x, b1.y, b1.z, b1.w};
#pragma unroll
            for (int i = 0; i < 8; ++i)
#pragma unroll
                for (int j = 0; j < 8; ++j)
                    acc[i][j] = fmaf(av[i], bv[j], acc[i][j]);
        }
    }

    float* __restrict__ Gb = G + (size_t)b * Cn * Cn;
#pragma unroll
    for (int i = 0; i < 8; ++i) {
        const int ri = (i < 4) ? (4 * ty + i) : (64 + 4 * ty + (i - 4));
#pragma unroll
        for (int j = 0; j < 8; ++j) {
            const int cj = (j < 4) ? (4 * tx + j) : (64 + 4 * tx + (j - 4));
            atomicAdd(&Gb[(size_t)ri * Cn + cj], acc[i][j]);
        }
    }
}

// ---------------------------------------------------------------------------
// Kernel 2: M[row][d] = rowmax(G[row]) - G[row][d]  (fp32)
// ---------------------------------------------------------------------------
__global__ __launch_bounds__(128) void maxsub_kernel(const float* __restrict__ G,
                                                     float* __restrict__ M) {
    const int row = blockIdx.x;
    const int l = threadIdx.x;
    const float v = G[(size_t)row * Cn + l];
    __shared__ float red[128];
    red[l] = v;
    __syncthreads();
#pragma unroll
    for (int s = 64; s > 0; s >>= 1) {
        if (l < s) red[l] = fmaxf(red[l], red[l + s]);
        __syncthreads();
    }
    M[(size_t)row * Cn + l] = red[0] - v;
}

// ---------------------------------------------------------------------------
// Kernel 3: Y[b] = M[b] @ f[b]  ([128x128]x[128x16384]), fp32 accumulate.
// grid = 16 b * 128 ntiles = 2048 blocks, 256 thr. Tile 128c x 128n, K=128.
// ---------------------------------------------------------------------------
__global__ __launch_bounds__(256) void ymm_kernel(const float* __restrict__ M,
                                                  const float* __restrict__ x,
                                                  float* __restrict__ Y) {
    const int bid = blockIdx.x;
    const int nt = bid & 127;
    const int b  = bid >> 7;
    const int n0 = nt << 7;
    const float* __restrict__ fb = x + (size_t)b * Cn * Nn;
    const float* __restrict__ Mb = M + (size_t)b * Cn * Cn;

    __shared__ __align__(16) float SA[32][132];   // [k][c]
    __shared__ __align__(16) float SB[32][132];   // [k][n]

    const int tid = threadIdx.x;
    const int tx = tid & 15, ty = tid >> 4;

    float acc[8][8];
#pragma unroll
    for (int i = 0; i < 8; ++i)
#pragma unroll
        for (int j = 0; j < 8; ++j) acc[i][j] = 0.0f;

    for (int kk = 0; kk < Cn; kk += 32) {
        __syncthreads();
        // stage A: M rows c=0..127, cols kk..kk+31 (transposed scalar stores)
#pragma unroll
        for (int p = 0; p < 4; ++p) {
            const int q  = tid + (p << 8);
            const int c  = q >> 3;
            const int k4 = (q & 7) << 2;
            const float4 v = *(const float4*)(Mb + (size_t)c * Cn + kk + k4);
            SA[k4 + 0][c] = v.x; SA[k4 + 1][c] = v.y;
            SA[k4 + 2][c] = v.z; SA[k4 + 3][c] = v.w;
        }
        // stage B: f rows d=kk..kk+31, cols n0..n0+127 (direct float4 stores)
#pragma unroll
        for (int p = 0; p < 4; ++p) {
            const int q  = tid + (p << 8);
            const int d  = q >> 5;           // 0..31
            const int c4 = (q & 31) << 2;    // 0,4,...,124
            const float4 v = *(const float4*)(fb + (size_t)(kk + d) * Nn + n0 + c4);
            *(float4*)&SB[d][c4] = v;
        }
        __syncthreads();
#pragma unroll
        for (int k = 0; k < 32; ++k) {
            const float4 a0 = *(const float4*)&SA[k][4 * ty];
            const float4 a1 = *(const float4*)&SA[k][64 + 4 * ty];
            const float4 b0 = *(const float4*)&SB[k][4 * tx];
            const float4 b1 = *(const float4*)&SB[k][64 + 4 * tx];
            const float av[8] = {a0.x, a0.y, a0.z, a0.w, a1.x, a1.y, a1.z, a1.w};
            const float bv[8] = {b0.x, b0.y, b0.z, b0.w, b1.x, b1.y, b1.z, b1.w};
#pragma unroll
            for (int i = 0; i < 8; ++i)
#pragma unroll
                for (int j = 0; j < 8; ++j)
                    acc[i][j] = fmaf(av[i], bv[j], acc[i][j]);
        }
    }

    float* __restrict__ Yb = Y + (size_t)b * Cn * Nn;
#pragma unroll
    for (int i = 0; i < 8; ++i) {
        const int ri = (i < 4) ? (4 * ty + i) : (64 + 4 * ty + (i - 4));
        float4 o0 = {acc[i][0], acc[i][1], acc[i][2], acc[i][3]};
        float4 o1 = {acc[i][4], acc[i][5], acc[i][6], acc[i][7]};
        *(float4*)(Yb + (size_t)ri * Nn + n0 + 4 * tx) = o0;
        *(float4*)(Yb + (size_t)ri * Nn + n0 + 64 + 4 * tx) = o1;
    }
}

// ---------------------------------------------------------------------------
// Kernel 4 (fused): depthwise 3x3 conv + bias + softmax(dim=W) + epilogue
//   atten = softmax(conv(Y)+bias); out = gamma*atten + x
// One block per (b,c) plane; plane staged in LDS [128][131] with col offset+1
// (zero borders). Thread t owns row h=t>>1, cols (t&1)*64..+63 (2x32 chunks).
// ---------------------------------------------------------------------------
__global__ __launch_bounds__(256) void conv_softmax_kernel(const float* __restrict__ Yin,
                                                           const float* __restrict__ wgt,
                                                           const float* __restrict__ bias,
                                                           const float* __restrict__ x,
                                                           const float* __restrict__ gamma,
                                                           float* __restrict__ out,
                                                           float* __restrict__ atten) {
    const int pid = blockIdx.x;              // b*Cn + c
    const int c = pid & (Cn - 1);
    const size_t pbase = (size_t)pid * Nn;

    __shared__ __align__(16) float P[128][131];   // cols: 0 and 129 are zero borders

    const int tid = threadIdx.x;

    // load plane (16 float4 per thread) + zero borders
#pragma unroll
    for (int p = 0; p < 16; ++p) {
        const int q = tid + (p << 8);
        const int row = q >> 5;
        const int c4 = (q & 31) << 2;
        const float4 v = *(const float4*)(Yin + pbase + (size_t)row * Wn + c4);
        P[row][1 + c4 + 0] = v.x; P[row][1 + c4 + 1] = v.y;
        P[row][1 + c4 + 2] = v.z; P[row][1 + c4 + 3] = v.w;
    }
    if (tid < 128) { P[tid][0] = 0.0f; P[tid][129] = 0.0f; }

    // weights / bias (wave-uniform)
    float wk[9];
#pragma unroll
    for (int i = 0; i < 9; ++i) wk[i] = wgt[c * 9 + i];
    const float bs = bias[c];
    const float g = gamma[0];

    __syncthreads();

    const int h = tid >> 1;
    const int c0 = (tid & 1) << 6;   // 0 or 64

    float acc0[32], acc1[32];
#pragma unroll
    for (int w = 0; w < 32; ++w) { acc0[w] = bs; acc1[w] = bs; }

#pragma unroll
    for (int chunk = 0; chunk < 2; ++chunk) {
        float* acc = chunk ? acc1 : acc0;
        const int cb = c0 + (chunk << 5);
#pragma unroll
        for (int kh = 0; kh < 3; ++kh) {
            const int hh = h + kh - 1;
            if (hh < 0 || hh >= Hn) continue;
            float r[34];
#pragma unroll
            for (int i = 0; i < 34; ++i) r[i] = P[hh][cb + i];
            const float w0 = wk[kh * 3 + 0], w1 = wk[kh * 3 + 1], w2 = wk[kh * 3 + 2];
#pragma unroll
            for (int w = 0; w < 32; ++w)
                acc[w] = fmaf(w0, r[w], fmaf(w1, r[w + 1], fmaf(w2, r[w + 2], acc[w])));
        }
    }

    // softmax over the 128-col row: this thread has 64, partner (tid^1) has 64
    float m = -1e30f;
#pragma unroll
    for (int w = 0; w < 32; ++w) m = fmaxf(m, fmaxf(acc0[w], acc1[w]));
    m = fmaxf(m, __shfl_xor(m, 1));
    float s = 0.0f;
#pragma unroll
    for (int w = 0; w < 32; ++w) { acc0[w] = __expf(acc0[w] - m); s += acc0[w]; }
#pragma unroll
    for (int w = 0; w < 32; ++w) { acc1[w] = __expf(acc1[w] - m); s += acc1[w]; }
    s += __shfl_xor(s, 1);
    const float inv = 1.0f / s;

    __syncthreads();   // all conv reads of P done before overwrite

    // store atten back into P (same +1 layout) for coalesced writeout
#pragma unroll
    for (int w = 0; w < 32; ++w) {
        P[h][1 + c0 + w] = acc0[w] * inv;
        P[h][1 + c0 + 32 + w] = acc1[w] * inv;
    }
    __syncthreads();

    // coalesced writeout: atten and out = gamma*atten + x
#pragma unroll
    for (int p = 0; p < 16; ++p) {
        const int q = tid + (p << 8);
        const int row = q >> 5;
        const int c4 = (q & 31) << 2;
        float4 a;
        a.x = P[row][1 + c4 + 0]; a.y = P[row][1 + c4 + 1];
        a.z = P[row][1 + c4 + 2]; a.w = P[row][1 + c4 + 3];
        const float4 xv = *(const float4*)(x + pbase + (size_t)row * Wn + c4);
        float4 o;
        o.x = fmaf(g, a.x, xv.x); o.y = fmaf(g, a.y, xv.y);
        o.z = fmaf(g, a.z, xv.z); o.w = fmaf(g, a.w, xv.w);
        *(float4*)(atten + pbase + (size_t)row * Wn + c4) = a;
        *(float4*)(out + pbase + (size_t)row * Wn + c4) = o;
    }
}

// ---------------------------------------------------------------------------
extern "C" void kernel_launch(void* const* d_in, const int* in_sizes, int n_in,
                              void* d_out, int out_size, void* d_ws, size_t ws_size,
                              hipStream_t stream) {
    const float* x     = (const float*)d_in[0];
    const float* wgt   = (const float*)d_in[1];
    const float* bias  = (const float*)d_in[2];
    const float* gamma = (const float*)d_in[3];

    float* out   = (float*)d_out;
    float* atten = out + (size_t)Bn * Cn * Nn;

    float* G = (float*)d_ws;                              // 1 MB
    float* M = G + (size_t)Bn * Cn * Cn;                  // +1 MB
    float* Y = out;   // reuse out-region as Y scratch; overwritten last

    hipMemsetAsync(G, 0, sizeof(float) * (size_t)Bn * Cn * Cn, stream);

    gram_kernel<<<Bn * 32, 256, 0, stream>>>(x, G);
    maxsub_kernel<<<Bn * Cn, 128, 0, stream>>>(G, M);
    ymm_kernel<<<Bn * 128, 256, 0, stream>>>(M, x, Y);
    conv_softmax_kernel<<<Bn * Cn, 256, 0, stream>>>(Y, wgt, bias, x, gamma, out, atten);
}

// Round 3
// 553.840 us; speedup vs baseline: 1.9240x; 1.1542x over previous
//
#include <hip/hip_runtime.h>

#define Bn 16
#define Cn 128
#define Hn 128
#define Wn 128
#define Nn (Hn * Wn)   // 16384

typedef __attribute__((ext_vector_type(8))) short bf16x8;   // 8 bf16 = 4 VGPRs
typedef __attribute__((ext_vector_type(4))) float f32x4;

// round-to-nearest-even fp32 -> bf16 (bit pattern in ushort)
__device__ __forceinline__ unsigned short bfh(float f) {
    unsigned u = __float_as_uint(f);
    u += 0x7FFFu + ((u >> 16) & 1u);
    return (unsigned short)(u >> 16);
}
__device__ __forceinline__ float bf2f(unsigned short h) {
    return __uint_as_float(((unsigned)h) << 16);
}

__device__ __forceinline__ bf16x8 ldfrag(const unsigned short* S, int row, int quad) {
    return *(const bf16x8*)(S + row * 40 + quad * 8);
}

// ---------------------------------------------------------------------------
// colsum[b][n] = sum_c f[b][c][n]   (exact fp32; needed for the rank-1 term)
// grid = 16 b * 16 ntiles = 256 blocks, 256 thr; each thread one float4 col-group
// ---------------------------------------------------------------------------
__global__ __launch_bounds__(256) void colsum_kernel(const float* __restrict__ x,
                                                     float* __restrict__ colsum) {
    const int b = blockIdx.x >> 4;
    const int nt = blockIdx.x & 15;
    const int n4 = (nt << 10) + (threadIdx.x << 2);
    const float* __restrict__ fb = x + (size_t)b * Cn * Nn;
    float4 s = {0.f, 0.f, 0.f, 0.f};
    for (int c = 0; c < Cn; ++c) {
        const float4 v = *(const float4*)(fb + (size_t)c * Nn + n4);
        s.x += v.x; s.y += v.y; s.z += v.z; s.w += v.w;
    }
    *(float4*)(colsum + (size_t)b * Nn + n4) = s;
}

// ---------------------------------------------------------------------------
// Kernel 1: G[b] = f . f^T via bf16-split MFMA (3-term), split-K(32) + atomics
// grid = 16 b * 32 ksplit = 512 blocks, 256 thr (4 waves, 2x2 of 64x64 tiles)
// ---------------------------------------------------------------------------
__global__ __launch_bounds__(256, 2) void gram_mfma(const float* __restrict__ x,
                                                    float* __restrict__ G) {
    const int bid = blockIdx.x;
    const int ks = bid & 31;
    const int b = bid >> 5;
    const float* __restrict__ fb = x + (size_t)b * Cn * Nn;
    const int k0 = ks << 9;   // 512-wide K slice

    __shared__ __align__(16) unsigned short Shi[128 * 40];
    __shared__ __align__(16) unsigned short Slo[128 * 40];

    const int tid = threadIdx.x;
    const int wave = tid >> 6, lane = tid & 63;
    const int m = lane & 15, quad = lane >> 4;
    const int wr = (wave >> 1) << 6;   // wave row base (0/64)
    const int wc = (wave & 1) << 6;    // wave col base (0/64)

    f32x4 acc[4][4];
#pragma unroll
    for (int i = 0; i < 4; ++i)
#pragma unroll
        for (int j = 0; j < 4; ++j) acc[i][j] = (f32x4){0.f, 0.f, 0.f, 0.f};

    for (int ck = 0; ck < 512; ck += 32) {
        __syncthreads();
        // stage 128c x 32k, fp32 -> (hi,lo) bf16
#pragma unroll
        for (int p = 0; p < 4; ++p) {
            const int q = tid + (p << 8);
            const int c = q >> 3;
            const int k4 = (q & 7) << 2;
            const float4 v = *(const float4*)(fb + (size_t)c * Nn + k0 + ck + k4);
            const float f0[4] = {v.x, v.y, v.z, v.w};
            unsigned short h[4], l[4];
#pragma unroll
            for (int e = 0; e < 4; ++e) {
                h[e] = bfh(f0[e]);
                l[e] = bfh(f0[e] - bf2f(h[e]));
            }
            *(ushort4*)(Shi + c * 40 + k4) = make_ushort4(h[0], h[1], h[2], h[3]);
            *(ushort4*)(Slo + c * 40 + k4) = make_ushort4(l[0], l[1], l[2], l[3]);
        }
        __syncthreads();

        bf16x8 Ah[4], Al[4], Bh[4], Bl[4];
#pragma unroll
        for (int i = 0; i < 4; ++i) {
            Ah[i] = ldfrag(Shi, wr + (i << 4) + m, quad);
            Al[i] = ldfrag(Slo, wr + (i << 4) + m, quad);
            Bh[i] = ldfrag(Shi, wc + (i << 4) + m, quad);
            Bl[i] = ldfrag(Slo, wc + (i << 4) + m, quad);
        }
#pragma unroll
        for (int i = 0; i < 4; ++i)
#pragma unroll
            for (int j = 0; j < 4; ++j) {
                acc[i][j] = __builtin_amdgcn_mfma_f32_16x16x32_bf16(Ah[i], Bh[j], acc[i][j], 0, 0, 0);
                acc[i][j] = __builtin_amdgcn_mfma_f32_16x16x32_bf16(Ah[i], Bl[j], acc[i][j], 0, 0, 0);
                acc[i][j] = __builtin_amdgcn_mfma_f32_16x16x32_bf16(Al[i], Bh[j], acc[i][j], 0, 0, 0);
            }
    }

    float* __restrict__ Gb = G + (size_t)b * Cn * Cn;
#pragma unroll
    for (int i = 0; i < 4; ++i)
#pragma unroll
        for (int j = 0; j < 4; ++j)
#pragma unroll
            for (int r = 0; r < 4; ++r) {
                const int row = wr + (i << 4) + (quad << 2) + r;
                const int col = wc + (j << 4) + m;
                atomicAdd(&Gb[(size_t)row * Cn + col], acc[i][j][r]);
            }
}

// ---------------------------------------------------------------------------
// Kernel 2 (prep): per row c of G[b]: rowmax (incl diag), Gdiag, and
// L = -(G with diag zeroed) as bf16 hi/lo for the MFMA ymm.
// grid = 2048 rows, 128 thr
// ---------------------------------------------------------------------------
__global__ __launch_bounds__(128) void prep_kernel(const float* __restrict__ G,
                                                   unsigned short* __restrict__ Lhi,
                                                   unsigned short* __restrict__ Llo,
                                                   float* __restrict__ rowmax,
                                                   float* __restrict__ gdiag) {
    const int row = blockIdx.x;          // b*128 + c
    const int c = row & 127;
    const int t = threadIdx.x;
    const float v = G[(size_t)row * Cn + t];
    __shared__ float red[128];
    red[t] = v;
    __syncthreads();
#pragma unroll
    for (int s = 64; s > 0; s >>= 1) {
        if (t < s) red[t] = fmaxf(red[t], red[t + s]);
        __syncthreads();
    }
    if (t == 0) rowmax[row] = red[0];
    if (t == c) gdiag[row] = v;
    const float l = (t == c) ? 0.0f : -v;
    const unsigned short h = bfh(l);
    Lhi[(size_t)row * Cn + t] = h;
    Llo[(size_t)row * Cn + t] = bfh(l - bf2f(h));
}

// ---------------------------------------------------------------------------
// Kernel 3: Y[b] = rowmax (x) colsum - Gdiag o f + L @ f   (L = -Goff, bf16 MFMA)
// grid = 2048 blocks (XCD-swizzled so each XCD's L2 holds 2 batches' L), 256 thr
// per block: all 128 c, 128-wide n-tile, K(d) = 128 in chunks of 32
// ---------------------------------------------------------------------------
__global__ __launch_bounds__(256, 2) void ymm_mfma(const unsigned short* __restrict__ Lhi,
                                                   const unsigned short* __restrict__ Llo,
                                                   const float* __restrict__ x,
                                                   const float* __restrict__ colsum,
                                                   const float* __restrict__ rowmax,
                                                   const float* __restrict__ gdiag,
                                                   float* __restrict__ Y) {
    const int bid = blockIdx.x;
    const int xcd = bid & 7;
    const int j2 = bid >> 3;
    const int b = (xcd << 1) + (j2 & 1);   // XCD x owns batches 2x, 2x+1
    const int nt = j2 >> 1;                // 0..127
    const int n0 = nt << 7;

    const float* __restrict__ fb = x + (size_t)b * Cn * Nn;
    const unsigned short* __restrict__ Lhb = Lhi + (size_t)b * Cn * Cn;
    const unsigned short* __restrict__ Llb = Llo + (size_t)b * Cn * Cn;

    __shared__ __align__(16) unsigned short SAh[128 * 40];  // [c][d-chunk]
    __shared__ __align__(16) unsigned short SAl[128 * 40];
    __shared__ __align__(16) unsigned short SBh[128 * 40];  // [n][d-chunk] (transposed f)
    __shared__ __align__(16) unsigned short SBl[128 * 40];

    const int tid = threadIdx.x;
    const int wave = tid >> 6, lane = tid & 63;
    const int m = lane & 15, quad = lane >> 4;
    const int wrc = (wave >> 1) << 6;   // c base
    const int wn = (wave & 1) << 6;     // n base

    f32x4 acc[4][4];
#pragma unroll
    for (int i = 0; i < 4; ++i)
#pragma unroll
        for (int j = 0; j < 4; ++j) acc[i][j] = (f32x4){0.f, 0.f, 0.f, 0.f};

    for (int dd = 0; dd < Cn; dd += 32) {
        __syncthreads();
        // stage A (L, already bf16 in global): 128c x 32d copy
#pragma unroll
        for (int p = 0; p < 4; ++p) {
            const int q = tid + (p << 8);
            const int c = q >> 3;
            const int d4 = (q & 7) << 2;
            *(ushort4*)(SAh + c * 40 + d4) = *(const ushort4*)(Lhb + (size_t)c * Cn + dd + d4);
            *(ushort4*)(SAl + c * 40 + d4) = *(const ushort4*)(Llb + (size_t)c * Cn + dd + d4);
        }
        // stage B (f fp32 -> hi/lo), transposed: SB[n][d]; thread owns 1 n, 4 d
#pragma unroll
        for (int p = 0; p < 4; ++p) {
            const int q = tid + (p << 8);
            const int nl = q & 127;
            const int d4 = (q >> 7) << 2;
            unsigned short h[4], l[4];
#pragma unroll
            for (int e = 0; e < 4; ++e) {
                const float f0 = fb[(size_t)(dd + d4 + e) * Nn + n0 + nl];
                h[e] = bfh(f0);
                l[e] = bfh(f0 - bf2f(h[e]));
            }
            *(ushort4*)(SBh + nl * 40 + d4) = make_ushort4(h[0], h[1], h[2], h[3]);
            *(ushort4*)(SBl + nl * 40 + d4) = make_ushort4(l[0], l[1], l[2], l[3]);
        }
        __syncthreads();

        bf16x8 Ah[4], Al[4], Bh[4], Bl[4];
#pragma unroll
        for (int i = 0; i < 4; ++i) {
            Ah[i] = ldfrag(SAh, wrc + (i << 4) + m, quad);
            Al[i] = ldfrag(SAl, wrc + (i << 4) + m, quad);
            Bh[i] = ldfrag(SBh, wn + (i << 4) + m, quad);
            Bl[i] = ldfrag(SBl, wn + (i << 4) + m, quad);
        }
#pragma unroll
        for (int i = 0; i < 4; ++i)
#pragma unroll
            for (int j = 0; j < 4; ++j) {
                acc[i][j] = __builtin_amdgcn_mfma_f32_16x16x32_bf16(Ah[i], Bh[j], acc[i][j], 0, 0, 0);
                acc[i][j] = __builtin_amdgcn_mfma_f32_16x16x32_bf16(Ah[i], Bl[j], acc[i][j], 0, 0, 0);
                acc[i][j] = __builtin_amdgcn_mfma_f32_16x16x32_bf16(Al[i], Bh[j], acc[i][j], 0, 0, 0);
            }
    }

    // epilogue: Y = rowmax*colsum - gdiag*f + acc
    float* __restrict__ Yb = Y + (size_t)b * Cn * Nn;
#pragma unroll
    for (int i = 0; i < 4; ++i)
#pragma unroll
        for (int r = 0; r < 4; ++r) {
            const int c = wrc + (i << 4) + (quad << 2) + r;
            const float rm = rowmax[(b << 7) + c];
            const float gd = gdiag[(b << 7) + c];
#pragma unroll
            for (int j = 0; j < 4; ++j) {
                const int n = n0 + wn + (j << 4) + m;
                const float cs = colsum[(size_t)b * Nn + n];
                const float fv = fb[(size_t)c * Nn + n];
                Yb[(size_t)c * Nn + n] = fmaf(rm, cs, fmaf(-gd, fv, acc[i][j][r]));
            }
        }
}

// ---------------------------------------------------------------------------
// Kernel 4 (fused): depthwise 3x3 conv + bias + softmax(dim=W) + epilogue
// (unchanged from round 2 — known correct; optimize next round if dominant)
// ---------------------------------------------------------------------------
__global__ __launch_bounds__(256) void conv_softmax_kernel(const float* __restrict__ Yin,
                                                           const float* __restrict__ wgt,
                                                           const float* __restrict__ bias,
                                                           const float* __restrict__ x,
                                                           const float* __restrict__ gamma,
                                                           float* __restrict__ out,
                                                           float* __restrict__ atten) {
    const int pid = blockIdx.x;              // b*Cn + c
    const int c = pid & (Cn - 1);
    const size_t pbase = (size_t)pid * Nn;

    __shared__ __align__(16) float P[128][131];

    const int tid = threadIdx.x;

#pragma unroll
    for (int p = 0; p < 16; ++p) {
        const int q = tid + (p << 8);
        const int row = q >> 5;
        const int c4 = (q & 31) << 2;
        const float4 v = *(const float4*)(Yin + pbase + (size_t)row * Wn + c4);
        P[row][1 + c4 + 0] = v.x; P[row][1 + c4 + 1] = v.y;
        P[row][1 + c4 + 2] = v.z; P[row][1 + c4 + 3] = v.w;
    }
    if (tid < 128) { P[tid][0] = 0.0f; P[tid][129] = 0.0f; }

    float wk[9];
#pragma unroll
    for (int i = 0; i < 9; ++i) wk[i] = wgt[c * 9 + i];
    const float bs = bias[c];
    const float g = gamma[0];

    __syncthreads();

    const int h = tid >> 1;
    const int c0 = (tid & 1) << 6;

    float acc0[32], acc1[32];
#pragma unroll
    for (int w = 0; w < 32; ++w) { acc0[w] = bs; acc1[w] = bs; }

#pragma unroll
    for (int chunk = 0; chunk < 2; ++chunk) {
        float* acc = chunk ? acc1 : acc0;
        const int cb = c0 + (chunk << 5);
#pragma unroll
        for (int kh = 0; kh < 3; ++kh) {
            const int hh = h + kh - 1;
            if (hh < 0 || hh >= Hn) continue;
            float r[34];
#pragma unroll
            for (int i = 0; i < 34; ++i) r[i] = P[hh][cb + i];
            const float w0 = wk[kh * 3 + 0], w1 = wk[kh * 3 + 1], w2 = wk[kh * 3 + 2];
#pragma unroll
            for (int w = 0; w < 32; ++w)
                acc[w] = fmaf(w0, r[w], fmaf(w1, r[w + 1], fmaf(w2, r[w + 2], acc[w])));
        }
    }

    float m = -1e30f;
#pragma unroll
    for (int w = 0; w < 32; ++w) m = fmaxf(m, fmaxf(acc0[w], acc1[w]));
    m = fmaxf(m, __shfl_xor(m, 1));
    float s = 0.0f;
#pragma unroll
    for (int w = 0; w < 32; ++w) { acc0[w] = __expf(acc0[w] - m); s += acc0[w]; }
#pragma unroll
    for (int w = 0; w < 32; ++w) { acc1[w] = __expf(acc1[w] - m); s += acc1[w]; }
    s += __shfl_xor(s, 1);
    const float inv = 1.0f / s;

    __syncthreads();

#pragma unroll
    for (int w = 0; w < 32; ++w) {
        P[h][1 + c0 + w] = acc0[w] * inv;
        P[h][1 + c0 + 32 + w] = acc1[w] * inv;
    }
    __syncthreads();

#pragma unroll
    for (int p = 0; p < 16; ++p) {
        const int q = tid + (p << 8);
        const int row = q >> 5;
        const int c4 = (q & 31) << 2;
        float4 a;
        a.x = P[row][1 + c4 + 0]; a.y = P[row][1 + c4 + 1];
        a.z = P[row][1 + c4 + 2]; a.w = P[row][1 + c4 + 3];
        const float4 xv = *(const float4*)(x + pbase + (size_t)row * Wn + c4);
        float4 o;
        o.x = fmaf(g, a.x, xv.x); o.y = fmaf(g, a.y, xv.y);
        o.z = fmaf(g, a.z, xv.z); o.w = fmaf(g, a.w, xv.w);
        *(float4*)(atten + pbase + (size_t)row * Wn + c4) = a;
        *(float4*)(out + pbase + (size_t)row * Wn + c4) = o;
    }
}

// ---------------------------------------------------------------------------
extern "C" void kernel_launch(void* const* d_in, const int* in_sizes, int n_in,
                              void* d_out, int out_size, void* d_ws, size_t ws_size,
                              hipStream_t stream) {
    const float* x     = (const float*)d_in[0];
    const float* wgt   = (const float*)d_in[1];
    const float* bias  = (const float*)d_in[2];
    const float* gamma = (const float*)d_in[3];

    float* out   = (float*)d_out;
    float* atten = out + (size_t)Bn * Cn * Nn;

    // ws layout (3.0 MB): G | colsum | Lhi | Llo
    float* G = (float*)d_ws;                                   // 1 MB
    float* colsum = G + (size_t)Bn * Cn * Cn;                  // 1 MB
    unsigned short* Lhi = (unsigned short*)(colsum + (size_t)Bn * Nn);  // 0.5 MB
    unsigned short* Llo = Lhi + (size_t)Bn * Cn * Cn;          // 0.5 MB
    // small arrays live at the head of the atten region (free until K4)
    float* rowmax = atten;            // 2048 floats
    float* gdiag  = atten + 2048;     // 2048 floats

    float* Y = out;   // out-region reused as Y scratch; overwritten by K4

    hipMemsetAsync(G, 0, sizeof(float) * (size_t)Bn * Cn * Cn, stream);

    colsum_kernel<<<Bn * 16, 256, 0, stream>>>(x, colsum);
    gram_mfma<<<Bn * 32, 256, 0, stream>>>(x, G);
    prep_kernel<<<Bn * Cn, 128, 0, stream>>>(G, Lhi, Llo, rowmax, gdiag);
    ymm_mfma<<<Bn * 128, 256, 0, stream>>>(Lhi, Llo, x, colsum, rowmax, gdiag, Y);
    conv_softmax_kernel<<<Bn * Cn, 256, 0, stream>>>(Y, wgt, bias, x, gamma, out, atten);
}